// Round 13
// baseline (560.882 us; speedup 1.0000x reference)
//
#include <hip/hip_runtime.h>
#include <stdint.h>

#define N 2048
#define BATCH 8
#define NROWS (BATCH * N)   // 16384
#define CAPN 256            // shortlist capacity per row
#define EXQ 2048            // event ring size (>= max pushes, see proof)
#define INV 0xFFFFFFFFu

typedef unsigned long long u64;
typedef unsigned u32;

#define DEADK 0xFFFFFFFFFFFFFFFFull

// ---------------- DPP wave64 reductions -----------------------------------
__device__ __forceinline__ unsigned wave_umin_bcast(unsigned x) {
#define DPP_MIN(ctrl)                                                          \
  {                                                                            \
    unsigned t = (unsigned)__builtin_amdgcn_update_dpp((int)x, (int)x, ctrl,   \
                                                       0xf, 0xf, false);       \
    x = t < x ? t : x;                                                         \
  }
  DPP_MIN(0x111) DPP_MIN(0x112) DPP_MIN(0x114) DPP_MIN(0x118)
  DPP_MIN(0x142) DPP_MIN(0x143)
#undef DPP_MIN
  return (unsigned)__builtin_amdgcn_readlane((int)x, 63);
}

__device__ __forceinline__ unsigned wave_umax_bcast(unsigned x) {
#define DPP_MAX(ctrl)                                                          \
  {                                                                            \
    unsigned t = (unsigned)__builtin_amdgcn_update_dpp((int)x, (int)x, ctrl,   \
                                                       0xf, 0xf, false);       \
    x = t > x ? t : x;                                                         \
  }
  DPP_MAX(0x111) DPP_MAX(0x112) DPP_MAX(0x114) DPP_MAX(0x118)
  DPP_MAX(0x142) DPP_MAX(0x143)
#undef DPP_MAX
  return (unsigned)__builtin_amdgcn_readlane((int)x, 63);
}

#define DPP64_MIN(x, ctrl)                                                     \
  {                                                                            \
    u32 lo_ = (u32)(x), hi_ = (u32)((x) >> 32);                                \
    u32 tlo_ = (u32)__builtin_amdgcn_update_dpp((int)lo_, (int)lo_, (ctrl),    \
                                                0xf, 0xf, false);              \
    u32 thi_ = (u32)__builtin_amdgcn_update_dpp((int)hi_, (int)hi_, (ctrl),    \
                                                0xf, 0xf, false);              \
    u64 t_ = ((u64)thi_ << 32) | tlo_;                                         \
    x = t_ < x ? t_ : x;                                                       \
  }

__device__ __forceinline__ u64 wave_min64_l63(u64 x) {
  DPP64_MIN(x, 0x111) DPP64_MIN(x, 0x112) DPP64_MIN(x, 0x114)
  DPP64_MIN(x, 0x118) DPP64_MIN(x, 0x142) DPP64_MIN(x, 0x143)
  return x;
}

// Exact-order distance: ((dx*dx + dy*dy) + dz*dz), no FMA contraction, sqrtf.
#define DIST(qx, qy, qz, TX, TY, TZ, j, dout)                                  \
  do {                                                                         \
    _Pragma("clang fp contract(off)")                                          \
    float dx_ = (qx) - (TX)[j];                                                \
    float dy_ = (qy) - (TY)[j];                                                \
    float dz_ = (qz) - (TZ)[j];                                                \
    float s_ = dx_ * dx_ + dy_ * dy_ + dz_ * dz_;                              \
    dout = sqrtf(s_);                                                          \
  } while (0)

// ---------------- Phase 1a: tau-shortlist (proven R2-R12) ------------------
__global__ __launch_bounds__(256, 1)
void emd_shortlist_kernel(const float* __restrict__ pred,
                          const float* __restrict__ target,
                          u64* __restrict__ keys,
                          u32* __restrict__ cnts) {
    __shared__ float tx[N], ty[N], tz[N];
    const int b  = blockIdx.x >> 9;
    const int r0 = (blockIdx.x & 511) << 2;
    const float* tb = target + (size_t)b * N * 3;

    for (int idx = threadIdx.x; idx < 3 * N; idx += 256) {
        float v = tb[idx];
        int n = idx / 3, c = idx - 3 * n;
        if (c == 0) tx[n] = v; else if (c == 1) ty[n] = v; else tz[n] = v;
    }
    __syncthreads();

    const int wid = threadIdx.x >> 6, lane = threadIdx.x & 63;
    const int i = r0 + wid;
    const size_t row = (size_t)b * N + i;
    const float* pb = pred + row * 3;
    const float qx = pb[0], qy = pb[1], qz = pb[2];

    float d[32];
    float m = 3.4e38f;
    #pragma unroll
    for (int c = 0; c < 32; ++c) {
        const int j = (c << 6) + lane;
        float dd;
        DIST(qx, qy, qz, tx, ty, tz, j, dd);
        d[c] = dd;
        m = fminf(m, dd);
    }

    unsigned mb = __float_as_uint(m);
    {   // pair-min (xor1 quad_perm): tau = max of 32 min-of-64 -> E[cnt]~130
        unsigned t = (unsigned)__builtin_amdgcn_update_dpp((int)mb, (int)mb,
                                                           0x0B1, 0xf, 0xf, false);
        mb = t < mb ? t : mb;
    }
    const unsigned tau = wave_umax_bcast(mb);
    const float tauf = __uint_as_float(tau);

    u64* krow = keys + row * (size_t)CAPN;
    unsigned base = 0;
    #pragma unroll
    for (int c = 0; c < 32; ++c) {
        const bool p = d[c] <= tauf;
        const u64 bm = __ballot(p);
        if (p) {
            unsigned off = base + (unsigned)__popcll(bm & ((1ull << lane) - 1ull));
            if (off < (unsigned)CAPN)
                krow[off] = ((u64)__float_as_uint(d[c]) << 32) |
                            (unsigned)((c << 6) + lane);
        }
        base += (unsigned)__popcll(bm);
    }
    if (lane == 0) cnts[row] = base;
}

// ---------------- Phase 1b: in-place sorted top-64 extraction --------------
#define CSWAP(a, b)                                                            \
  { u64 mn_ = (a) < (b) ? (a) : (b); u64 mx_ = (a) < (b) ? (b) : (a);          \
    (a) = mn_; (b) = mx_; }

__global__ __launch_bounds__(256, 1)
void emd_sort64_kernel(u64* __restrict__ keys, const u32* __restrict__ cnts) {
    const int wid = threadIdx.x >> 6, lane = threadIdx.x & 63;
    const size_t row = (size_t)blockIdx.x * 4 + wid;
    u64* krow = keys + row * (size_t)CAPN;

    const u32 cnt = cnts[row];
    const u32 lim = (cnt > (u32)CAPN) ? 0u : cnt;   // overflow -> no candidates

    u64 k0 = ((u32)lane       < lim) ? krow[lane      ] : DEADK;
    u64 k1 = ((u32)lane + 64  < lim) ? krow[lane + 64 ] : DEADK;
    u64 k2 = ((u32)lane + 128 < lim) ? krow[lane + 128] : DEADK;
    u64 k3 = ((u32)lane + 192 < lim) ? krow[lane + 192] : DEADK;

    CSWAP(k0, k1) CSWAP(k2, k3) CSWAP(k0, k2) CSWAP(k1, k3) CSWAP(k1, k2)

    u64 mykey = DEADK;
    for (int it = 0; it < 64; ++it) {
        u64 wm = wave_min64_l63(k0);
        u32 wlo = (u32)__builtin_amdgcn_readlane((int)(u32)wm, 63);
        u32 whi = (u32)__builtin_amdgcn_readlane((int)(u32)(wm >> 32), 63);
        if (whi == 0xFFFFFFFFu) break;            // all exhausted (cnt < 64)
        const u64 wkey = ((u64)whi << 32) | wlo;
        mykey = (lane == it) ? wkey : mykey;      // capture in lane `it`
        const bool eq = (k0 == wkey);             // unique (distinct j)
        k0 = eq ? k1 : k0; k1 = eq ? k2 : k1; k2 = eq ? k3 : k2;
        k3 = eq ? DEADK : k3;
    }
    krow[lane] = mykey;   // in-place: all reads consumed above
}

// ---------------- Phase 2: DA, LDS walks + adoption cascades ---------------
// THEOREM (HW-validated R9-R12, absmax 0.0): greedy row-order matching ==
// unique stable matching == row-proposing DA under ANY proposal order;
// holder[] via atomicMin is monotone => rejections permanent.
// Stage 1: 2048 walks, ALL-LDS: u16 top-16 target lists (d never needed until
// the final recomputed sum); hop = ds_read_u16 + LDS atomicMin; displacer
// adopts the displaced row. Walks passing 16 entries (~120/batch) or hitting
// the sentinel push ONE event each and stop => talloc <= 2048 = EXQ, and
// after the barrier talloc is FROZEN (stage 2 adopts instead of pushing).
// Stage 2: waves claim events by atomicAdd(head) until head >= talloc -- no
// spinning, no done-counter (R12's issue-burning poll deleted). Event resolve:
// list-resume (one 8B/lane load of the sorted top-64; ballot; propose in list
// order, each atomicMin-verified; pre-check exclusions permanent by
// monotonicity) else full LDS scan over {j: holder[j]>r} (nonempty for any
// unmatched r) with DISTs hoisted out of the race-retry loop. Displacement ->
// in-wave adoption, cascade continues until a free target.
__global__ __launch_bounds__(1024, 1)
void emd_da4_kernel(const float* __restrict__ pred,
                    const float* __restrict__ target,
                    const u64* __restrict__ keys,
                    float* __restrict__ batch_emd) {
    __shared__ float tx[N], ty[N], tz[N];        // 24KB targets
    __shared__ float px[N], py[N], pz[N];        // 24KB preds
    __shared__ u32 holder[N];                    // 8KB
    __shared__ unsigned short posn[N];           // 4KB
    __shared__ unsigned short list16[N * 16];    // 64KB u16 target lists
    __shared__ u32 exq[EXQ];                     // 8KB event ring
    __shared__ u32 talloc, head;
    __shared__ double dsum[1024];                // 8KB

    const int tid = threadIdx.x;
    const int lane = tid & 63;
    const int b = blockIdx.x;
    const float* pb = pred + (size_t)b * N * 3;
    const float* tb = target + (size_t)b * N * 3;
    const u64* kb = keys + (size_t)b * N * (size_t)CAPN;

    for (int idx = tid; idx < 3 * N; idx += 1024) {
        float vp = pb[idx], vt = tb[idx];
        int n = idx / 3, c = idx - 3 * n;
        if (c == 0)      { px[n] = vp; tx[n] = vt; }
        else if (c == 1) { py[n] = vp; ty[n] = vt; }
        else             { pz[n] = vp; tz[n] = vt; }
    }
    for (int j = tid; j < N; j += 1024) { holder[j] = INV; posn[j] = 0; }
    if (tid == 0) { talloc = 0; head = 0; }
    // compact u16 lists: entry e of row = j of e-th smallest key (0xFFFF dead)
    for (int idx = tid; idx < N * 16; idx += 1024) {
        const int row = idx >> 4, e = idx & 15;
        const u64 key = kb[(size_t)row * CAPN + e];
        list16[idx] = ((u32)(key >> 32) == INV)
                          ? (unsigned short)0xFFFF
                          : (unsigned short)((u32)key & (N - 1));
    }
    __syncthreads();

    // ---- stage 1: all-LDS walks with adoption ----
    #pragma unroll
    for (int k = 0; k < 2; ++k) {
        u32 r = (u32)tid + (k ? 1024u : 0u);
        u32 p = 0;
        for (int guard = 0; guard < 200000; ++guard) {
            if (p >= 16) {              // deep walk -> defer to stage 2
                posn[r] = 16;           // entries 0..15 permanently rejected
                const u32 s = atomicAdd(&talloc, 1u);
                exq[s & (EXQ - 1)] = r;
                break;
            }
            const u32 t = (u32)list16[(r << 4) + p];
            if (t == 0xFFFFu) {         // sorted list ended (overflow row)
                posn[r] = 64;
                const u32 s = atomicAdd(&talloc, 1u);
                exq[s & (EXQ - 1)] = r;
                break;
            }
            const u32 old = atomicMin(&holder[t], r);
            if (old < r) { ++p; continue; }          // rejected (permanent)
            posn[r] = (unsigned short)(p + 1);       // held
            if (old == INV) break;                   // free target: chain done
            r = old; p = (u32)posn[r];               // ADOPT displaced row
        }
    }
    __syncthreads();

    // ---- stage 2: frozen event list, in-wave cascades, no polling ----
    const u32 TA = talloc;              // frozen: stage 2 never pushes
    for (int guard = 0; guard < 20000; ++guard) {
        u32 i = 0;
        if (lane == 0) i = atomicAdd(&head, 1u);
        i = (u32)__shfl((int)i, 0, 64);
        if (i >= TA) break;
        u32 r = exq[i & (EXQ - 1)];

        for (int cg = 0; cg < 200000; ++cg) {       // cascade with adoption
            const u32 p = (u32)posn[r];
            u32 nextr = INV;
            bool matched_free = false, resolved = false;

            if (p < 64) {
                // list-resume: one 8B/lane load of the row's sorted top-64
                const u64 key = kb[(size_t)r * CAPN + lane];
                const u32 dv = (u32)(key >> 32);
                const u32 t = (u32)key & (N - 1);
                const bool cand = ((u32)lane >= p) && (dv != INV) &&
                                  (holder[t] > r);
                u64 bal = __ballot(cand);
                while (bal) {                        // propose in list order
                    const int L = __ffsll((long long)bal) - 1;
                    const u32 tL = (u32)__builtin_amdgcn_readlane((int)t, L);
                    u32 old = 0;
                    if (lane == 0) old = atomicMin(&holder[tL], r);
                    old = (u32)__shfl((int)old, 0, 64);
                    if (old > r) {                   // held
                        if (lane == 0) posn[r] = (unsigned short)(L + 1);
                        resolved = true;
                        if (old == INV) matched_free = true; else nextr = old;
                        break;
                    }
                    bal &= ~(1ull << (u32)L);        // raced: permanent reject
                }
            }

            if (!resolved) {
                // full scan over {j: holder[j] > r}; DISTs hoisted from retry
                const float qx = px[r], qy = py[r], qz = pz[r];
                u32 dbits[32];
                #pragma unroll
                for (int c = 0; c < 32; ++c) {
                    const int j = (c << 6) + lane;
                    float dd;
                    DIST(qx, qy, qz, tx, ty, tz, j, dd);
                    dbits[c] = __float_as_uint(dd);
                }
                for (int rty = 0; rty < 100000; ++rty) {
                    u64 best = DEADK;
                    #pragma unroll 8
                    for (int c = 0; c < 32; ++c) {
                        const int j = (c << 6) + lane;
                        if (holder[j] > r) {
                            const u64 kk = ((u64)dbits[c] << 32) | (u32)j;
                            if (kk < best) best = kk;
                        }
                    }
                    const u64 wm = wave_min64_l63(best);
                    const u32 jw =
                        (u32)__builtin_amdgcn_readlane((int)(u32)wm, 63) & (N - 1);
                    u32 old = 0;
                    if (lane == 0) old = atomicMin(&holder[jw], r);
                    old = (u32)__shfl((int)old, 0, 64);
                    if (old < r) continue;           // lost race: set shrank
                    if (lane == 0) posn[r] = 64;
                    if (old == INV) matched_free = true; else nextr = old;
                    break;
                }
            }

            if (matched_free) break;                 // cascade ended
            r = nextr;                               // adopt, continue
        }
    }
    __syncthreads();

    // ---- final sum over targets (recomputed DIST bit-identical to keys) ---
    double s = 0.0;
    #pragma unroll
    for (int k = 0; k < 2; ++k) {
        const int t = tid + (k ? 1024 : 0);
        const u32 r = holder[t] & (N - 1);
        float dd;
        DIST(px[r], py[r], pz[r], tx, ty, tz, t, dd);
        s += (double)dd;
    }
    dsum[tid] = s;
    __syncthreads();
    for (int st = 512; st >= 1; st >>= 1) {
        if (tid < st) dsum[tid] += dsum[tid + st];
        __syncthreads();
    }
    if (tid == 0) batch_emd[b] = (float)(dsum[0] / N);
}

// ---------------- exact full-scan helper (tiny-ws fallback kernel) --------
__device__ __forceinline__ u64 full_scan_row(
    int lane, float qx, float qy, float qz,
    const float* tx, const float* ty, const float* tz,
    const unsigned char* used) {
  u32 dl = 0xFFFFFFFFu, jl = 0u;
  #pragma unroll 8
  for (int c = 0; c < 32; ++c) {
    const int j = (c << 6) + lane;
    if (!used[j]) {
      float dd;
      DIST(qx, qy, qz, tx, ty, tz, j, dd);
      const u32 db = __float_as_uint(dd);
      if (db < dl) { dl = db; jl = (u32)j; }
    }
  }
  const u32 dmin = wave_umin_bcast(dl);
  const u32 jc = (dl == dmin) ? jl : 0xFFFFFFFFu;
  const u32 jmin = wave_umin_bcast(jc);
  return ((u64)dmin << 32) | jmin;
}

__global__ __launch_bounds__(64, 1)
void emd_greedy_full_kernel(const float* __restrict__ pred,
                            const float* __restrict__ target,
                            float* __restrict__ batch_emd) {
    __shared__ float tx[N], ty[N], tz[N];
    __shared__ float qxs[N], qys[N], qzs[N];
    __shared__ unsigned char used[N];

    const int lane = threadIdx.x;
    const int b = blockIdx.x;
    const float* pb = pred + (size_t)b * N * 3;
    const float* tb = target + (size_t)b * N * 3;

    for (int idx = lane; idx < 3 * N; idx += 64) {
        float vp = pb[idx], vt = tb[idx];
        int n = idx / 3, c = idx - 3 * n;
        if (c == 0)      { qxs[n] = vp; tx[n] = vt; }
        else if (c == 1) { qys[n] = vp; ty[n] = vt; }
        else             { qzs[n] = vp; tz[n] = vt; }
    }
    for (int j = lane; j < N; j += 64) used[j] = 0;

    double sum = 0.0;
    for (int i = 0; i < N; ++i) {
        u64 fs = full_scan_row(lane, qxs[i], qys[i], qzs[i], tx, ty, tz, used);
        sum += (double)__uint_as_float((u32)(fs >> 32));
        if (lane == 0) used[(u32)fs] = 1;
    }
    if (lane == 0) batch_emd[b] = (float)(sum / N);
}

__global__ void emd_mean_kernel(const float* __restrict__ batch_emd,
                                float* __restrict__ out) {
    double s = 0.0;
    for (int b = 0; b < BATCH; ++b) s += (double)batch_emd[b];
    out[0] = (float)(s / BATCH);
}

extern "C" void kernel_launch(void* const* d_in, const int* in_sizes, int n_in,
                              void* d_out, int out_size, void* d_ws, size_t ws_size,
                              hipStream_t stream) {
    const float* pred   = (const float*)d_in[0];
    const float* target = (const float*)d_in[1];
    float* out = (float*)d_out;
    char* wsb = (char*)d_ws;

    const size_t keysz = (size_t)NROWS * CAPN * 8;   // 33.6 MB
    const size_t cntsz = (size_t)NROWS * 4;

    if (ws_size >= keysz + cntsz + 32) {
        u64* keys = (u64*)wsb;
        u32* cnts = (u32*)(wsb + keysz);
        float* emd = (float*)(wsb + keysz + cntsz);
        emd_shortlist_kernel<<<NROWS / 4, 256, 0, stream>>>(pred, target, keys, cnts);
        emd_sort64_kernel<<<NROWS / 4, 256, 0, stream>>>(keys, cnts);
        emd_da4_kernel<<<BATCH, 1024, 0, stream>>>(pred, target, keys, emd);
        emd_mean_kernel<<<1, 1, 0, stream>>>(emd, out);
    } else {
        float* emd = (float*)wsb;
        emd_greedy_full_kernel<<<BATCH, 64, 0, stream>>>(pred, target, emd);
        emd_mean_kernel<<<1, 1, 0, stream>>>(emd, out);
    }
}